// Round 1
// baseline (3713.506 us; speedup 1.0000x reference)
//
#include <hip/hip_runtime.h>
#include <hip/hip_bf16.h>
#include <math.h>

#define NF 128
#define EC 50
#define ECP 52            // padded edge-channel count (16B-aligned rows, zero pad)
#define ETILE 64          // edges per block-iteration
#define CUTOFF 0.8f
#define PI_F 3.14159265358979323846f

__device__ __forceinline__ float4 ld4(const float* p) { return *reinterpret_cast<const float4*>(p); }
__device__ __forceinline__ void st4(float* p, float4 v) { *reinterpret_cast<float4*>(p) = v; }

__device__ __forceinline__ float4 f4fma(float a, float4 w, float4 acc) {
    acc.x = fmaf(a, w.x, acc.x); acc.y = fmaf(a, w.y, acc.y);
    acc.z = fmaf(a, w.z, acc.z); acc.w = fmaf(a, w.w, acc.w);
    return acc;
}

__device__ __forceinline__ float sspf(float x) {
    // softplus(x) - log(2), numerically stable
    return fmaxf(x, 0.0f) + log1pf(expf(-fabsf(x))) - 0.69314718055994530942f;
}
__device__ __forceinline__ float4 ssp4(float4 v) {
    v.x = sspf(v.x); v.y = sspf(v.y); v.z = sspf(v.z); v.w = sspf(v.w);
    return v;
}
__device__ __forceinline__ float swishf(float x) {
    return x / (1.0f + expf(-x));
}

// -------------------------------------------------------------------------
// emb[n][0:64]  = swish(sin(t*coef_k)),  emb[n][64:128] = swish(cos(t*coef_k))
__global__ __launch_bounds__(256) void emb_kernel(const float* __restrict__ tt,
                                                  float* __restrict__ emb, int n) {
    int i = blockIdx.x * blockDim.x + threadIdx.x;
    if (i >= n * 64) return;
    int node = i >> 6, k = i & 63;
    float t = tt[node];
    // coef = exp(k * (-log(1000)/63))
    float coef = expf((float)k * (-6.9077552789821368f / 63.0f));
    float e = t * coef;
    emb[node * NF + k]      = swishf(sinf(e));
    emb[node * NF + 64 + k] = swishf(cosf(e));
}

// -------------------------------------------------------------------------
// out[N,128] = f(A[N,128] @ W[128,128] (+bias) (+extra))
// MODE 0: plain (no bias).  MODE 1: ssp(.+b).  MODE 2: ssp(.+b+extra).  MODE 3: .+b
template<int MODE>
__global__ __launch_bounds__(256) void node_gemm(const float* __restrict__ A,
                                                 const float* __restrict__ W,
                                                 const float* __restrict__ bias,
                                                 const float* __restrict__ extra,
                                                 float* __restrict__ out, int n) {
    extern __shared__ float sm[];
    float* W_lds = sm;            // 128*128
    float* A_lds = sm + NF * NF;  // 32*128
    const int tid = threadIdx.x;
    const int cg = tid & 31;      // channel group: 4 channels 4*cg..
    const int rg = tid >> 5;      // row group: rows rg*4..rg*4+3 within tile

    for (int idx = tid * 4; idx < NF * NF; idx += 1024)
        st4(W_lds + idx, ld4(W + idx));

    float4 bv = make_float4(0.f, 0.f, 0.f, 0.f);
    if (MODE != 0) bv = ld4(bias + 4 * cg);

    const int ntile = (n + 31) >> 5;
    for (int tile = blockIdx.x; tile < ntile; tile += gridDim.x) {
        const int base = tile << 5;
        __syncthreads();
        for (int idx = tid * 4; idx < 32 * NF; idx += 1024) {
            int r = idx >> 7;
            int row = base + r;
            float4 v = make_float4(0.f, 0.f, 0.f, 0.f);
            if (row < n) v = ld4(A + row * NF + (idx & 127));
            st4(A_lds + idx, v);
        }
        __syncthreads();

        float4 acc[4] = {bv, bv, bv, bv};
        #pragma unroll 8
        for (int k4 = 0; k4 < 32; k4++) {
            float4 w0 = ld4(W_lds + (4 * k4 + 0) * NF + 4 * cg);
            float4 w1 = ld4(W_lds + (4 * k4 + 1) * NF + 4 * cg);
            float4 w2 = ld4(W_lds + (4 * k4 + 2) * NF + 4 * cg);
            float4 w3 = ld4(W_lds + (4 * k4 + 3) * NF + 4 * cg);
            #pragma unroll
            for (int rr = 0; rr < 4; rr++) {
                float4 a = ld4(A_lds + (rg * 4 + rr) * NF + 4 * k4);
                acc[rr] = f4fma(a.x, w0, acc[rr]);
                acc[rr] = f4fma(a.y, w1, acc[rr]);
                acc[rr] = f4fma(a.z, w2, acc[rr]);
                acc[rr] = f4fma(a.w, w3, acc[rr]);
            }
        }
        #pragma unroll
        for (int rr = 0; rr < 4; rr++) {
            int row = base + rg * 4 + rr;
            if (row >= n) continue;
            float4 v = acc[rr];
            if (MODE == 2) {
                float4 e4 = ld4(extra + row * NF + 4 * cg);
                v.x += e4.x; v.y += e4.y; v.z += e4.z; v.w += e4.w;
            }
            if (MODE == 1 || MODE == 2) v = ssp4(v);
            st4(out + row * NF + 4 * cg, v);
        }
    }
}

// -------------------------------------------------------------------------
// Fused edge kernel: Wf = (ssp(ea@em1+b1)@em2+b2)*C ; agg[dst] += y[src]*Wf
__global__ __launch_bounds__(256) void edge_conv(const float* __restrict__ y,
                                                 const int* __restrict__ ei,
                                                 const float* __restrict__ elen,
                                                 const float* __restrict__ eattr,
                                                 const float* __restrict__ em1w,
                                                 const float* __restrict__ em1b,
                                                 const float* __restrict__ em2w,
                                                 const float* __restrict__ em2b,
                                                 float* __restrict__ agg, int E_) {
    extern __shared__ float sm[];
    float* em1_lds = sm;                      // ECP*128 (rows 50,51 zeroed)
    float* em2_lds = em1_lds + ECP * NF;      // 128*128
    float* ea_lds  = em2_lds + NF * NF;       // 64*ECP
    float* h_lds   = ea_lds + ETILE * ECP;    // 64*128
    float* C_sm    = h_lds + ETILE * NF;      // 64
    int*   src_s   = (int*)(C_sm + ETILE);    // 64
    int*   dst_s   = src_s + ETILE;           // 64

    const int tid = threadIdx.x;
    const int cg = tid & 31;   // channel group (4 channels)
    const int eg = tid >> 5;   // edge slot group, 8 edges each
    const int myE = eg * 8;

    // stage weights once per block
    for (int idx = tid * 4; idx < EC * NF; idx += 1024)
        st4(em1_lds + idx, ld4(em1w + idx));
    for (int idx = tid; idx < 2 * NF; idx += 256)
        em1_lds[EC * NF + idx] = 0.0f;
    for (int idx = tid * 4; idx < NF * NF; idx += 1024)
        st4(em2_lds + idx, ld4(em2w + idx));

    const float4 b1 = ld4(em1b + 4 * cg);
    const float4 b2 = ld4(em2b + 4 * cg);

    const int ntiles = (E_ + ETILE - 1) / ETILE;
    for (int tile = blockIdx.x; tile < ntiles; tile += gridDim.x) {
        const int base = tile * ETILE;
        __syncthreads();
        // stage edge meta
        for (int i = tid; i < ETILE; i += 256) {
            int e = base + i;
            float Cv = 0.0f; int s = 0, d = 0;
            if (e < E_) {
                s = ei[e]; d = ei[E_ + e];
                float len = elen[e];
                float c = 0.5f * (cosf(len * (PI_F / CUTOFF)) + 1.0f);
                Cv = (len <= CUTOFF && len >= 0.0f) ? c : 0.0f;
            }
            C_sm[i] = Cv; src_s[i] = s; dst_s[i] = d;
        }
        // stage edge_attr (zero-padded cols 50,51)
        for (int idx = tid; idx < ETILE * EC; idx += 256) {
            int i = idx / EC, k = idx - i * EC;
            int e = base + i;
            ea_lds[i * ECP + k] = (e < E_) ? eattr[(size_t)e * EC + k] : 0.0f;
        }
        for (int i = tid; i < ETILE * 2; i += 256)
            ea_lds[(i >> 1) * ECP + EC + (i & 1)] = 0.0f;
        __syncthreads();

        // ---- h = ssp(ea @ em1 + b1), each thread: 4 channels x 8 edges
        float4 acc[8];
        #pragma unroll
        for (int r = 0; r < 8; r++) acc[r] = b1;
        #pragma unroll 2
        for (int k4 = 0; k4 < ECP / 4; k4++) {
            float4 w0 = ld4(em1_lds + (4 * k4 + 0) * NF + 4 * cg);
            float4 w1 = ld4(em1_lds + (4 * k4 + 1) * NF + 4 * cg);
            float4 w2 = ld4(em1_lds + (4 * k4 + 2) * NF + 4 * cg);
            float4 w3 = ld4(em1_lds + (4 * k4 + 3) * NF + 4 * cg);
            #pragma unroll
            for (int r = 0; r < 8; r++) {
                float4 a = ld4(ea_lds + (myE + r) * ECP + 4 * k4);
                acc[r] = f4fma(a.x, w0, acc[r]);
                acc[r] = f4fma(a.y, w1, acc[r]);
                acc[r] = f4fma(a.z, w2, acc[r]);
                acc[r] = f4fma(a.w, w3, acc[r]);
            }
        }
        #pragma unroll
        for (int r = 0; r < 8; r++)
            st4(h_lds + (myE + r) * NF + 4 * cg, ssp4(acc[r]));
        __syncthreads();

        // ---- wf = h @ em2 + b2
        #pragma unroll
        for (int r = 0; r < 8; r++) acc[r] = b2;
        #pragma unroll 2
        for (int j4 = 0; j4 < NF / 4; j4++) {
            float4 w0 = ld4(em2_lds + (4 * j4 + 0) * NF + 4 * cg);
            float4 w1 = ld4(em2_lds + (4 * j4 + 1) * NF + 4 * cg);
            float4 w2 = ld4(em2_lds + (4 * j4 + 2) * NF + 4 * cg);
            float4 w3 = ld4(em2_lds + (4 * j4 + 3) * NF + 4 * cg);
            #pragma unroll
            for (int r = 0; r < 8; r++) {
                float4 h4 = ld4(h_lds + (myE + r) * NF + 4 * j4);
                acc[r] = f4fma(h4.x, w0, acc[r]);
                acc[r] = f4fma(h4.y, w1, acc[r]);
                acc[r] = f4fma(h4.z, w2, acc[r]);
                acc[r] = f4fma(h4.w, w3, acc[r]);
            }
        }

        // ---- epilogue: msg = y[src]*wf*C ; agg[dst] += msg
        #pragma unroll
        for (int r = 0; r < 8; r++) {
            int i = myE + r;
            int e = base + i;
            if (e >= E_) continue;
            float Cv = C_sm[i];
            if (Cv == 0.0f) continue;
            int s = src_s[i], d = dst_s[i];
            float4 yv = ld4(y + (size_t)s * NF + 4 * cg);
            float* ap = agg + (size_t)d * NF + 4 * cg;
            unsafeAtomicAdd(ap + 0, acc[r].x * Cv * yv.x);
            unsafeAtomicAdd(ap + 1, acc[r].y * Cv * yv.y);
            unsafeAtomicAdd(ap + 2, acc[r].z * Cv * yv.z);
            unsafeAtomicAdd(ap + 3, acc[r].w * Cv * yv.w);
        }
    }
}

// -------------------------------------------------------------------------
extern "C" void kernel_launch(void* const* d_in, const int* in_sizes, int n_in,
                              void* d_out, int out_size, void* d_ws, size_t ws_size,
                              hipStream_t stream) {
    const float* tt    = (const float*)d_in[0];
    const float* xx    = (const float*)d_in[1];
    const int*   ei    = (const int*)d_in[2];
    const float* elen  = (const float*)d_in[3];
    const float* eattr = (const float*)d_in[4];
    const float* em1w  = (const float*)d_in[5];
    const float* em1b  = (const float*)d_in[6];
    const float* em2w  = (const float*)d_in[7];
    const float* em2b  = (const float*)d_in[8];
    const float* c1m1w = (const float*)d_in[9];
    const float* c1m2w = (const float*)d_in[10];
    const float* c1m2b = (const float*)d_in[11];
    const float* c2m1w = (const float*)d_in[12];
    const float* c2m2w = (const float*)d_in[13];
    const float* c2m2b = (const float*)d_in[14];
    const float* tew   = (const float*)d_in[15];
    const float* teb   = (const float*)d_in[16];
    const float* linw  = (const float*)d_in[17];
    const float* linb  = (const float*)d_in[18];

    const int n  = in_sizes[0];      // N (tt is [N,1])
    const int E_ = in_sizes[2] / 2;  // edge_index is [2,E]
    float* out = (float*)d_out;

    const size_t NB = (size_t)n * NF;
    float* B0 = (float*)d_ws;   // y
    float* B1 = B0 + NB;        // agg
    float* B2 = B1 + NB;        // emb / x_mid
    float* B3 = B2 + NB;        // t / x3

    const size_t gemm_shmem = (size_t)(NF * NF + 32 * NF) * sizeof(float);   // 80 KB
    const size_t edge_shmem = (size_t)(ECP * NF + NF * NF + ETILE * ECP +
                                       ETILE * NF + ETILE) * sizeof(float) +
                              (size_t)(2 * ETILE) * sizeof(int);             // ~139 KB

    // time embedding -> B2 ; t = swish_emb @ te_w + te_b -> B3
    emb_kernel<<<(n * 64 + 255) / 256, 256, 0, stream>>>(tt, B2, n);
    node_gemm<3><<<512, 256, gemm_shmem, stream>>>(B2, tew, teb, nullptr, B3, n);

    // y1 = xx @ c1_m1w -> B0
    node_gemm<0><<<512, 256, gemm_shmem, stream>>>(xx, c1m1w, nullptr, nullptr, B0, n);

    // conv1 scatter
    hipMemsetAsync(B1, 0, NB * sizeof(float), stream);
    edge_conv<<<1024, 256, edge_shmem, stream>>>(B0, ei, elen, eattr,
                                                 em1w, em1b, em2w, em2b, B1, E_);

    // x_mid = ssp(agg @ c1_m2w + b + t) -> B2
    node_gemm<2><<<512, 256, gemm_shmem, stream>>>(B1, c1m2w, c1m2b, B3, B2, n);

    // y2 = x_mid @ c2_m1w -> B0
    node_gemm<0><<<512, 256, gemm_shmem, stream>>>(B2, c2m1w, nullptr, nullptr, B0, n);

    // conv2 scatter
    hipMemsetAsync(B1, 0, NB * sizeof(float), stream);
    edge_conv<<<1024, 256, edge_shmem, stream>>>(B0, ei, elen, eattr,
                                                 em1w, em1b, em2w, em2b, B1, E_);

    // x3 = ssp(agg @ c2_m2w + b) -> B3 ; out = ssp(x3 @ lin_w + b)
    node_gemm<1><<<512, 256, gemm_shmem, stream>>>(B1, c2m2w, c2m2b, nullptr, B3, n);
    node_gemm<1><<<512, 256, gemm_shmem, stream>>>(B3, linw, linb, nullptr, out, n);
}

// Round 2
// 3315.186 us; speedup vs baseline: 1.1202x; 1.1202x over previous
//
#include <hip/hip_runtime.h>
#include <hip/hip_bf16.h>
#include <math.h>

#define NF 128
#define EC 50
#define ECP 52            // padded edge-channel count (16B-aligned rows, zero pad)
#define ETILE 48          // edges per block-iteration
#define RE 6              // edges per thread
#define CUTOFF 0.8f
#define PI_F 3.14159265358979323846f

__device__ __forceinline__ float4 ld4(const float* p) { return *reinterpret_cast<const float4*>(p); }
__device__ __forceinline__ void st4(float* p, float4 v) { *reinterpret_cast<float4*>(p) = v; }

__device__ __forceinline__ float4 f4fma(float a, float4 w, float4 acc) {
    acc.x = fmaf(a, w.x, acc.x); acc.y = fmaf(a, w.y, acc.y);
    acc.z = fmaf(a, w.z, acc.z); acc.w = fmaf(a, w.w, acc.w);
    return acc;
}

__device__ __forceinline__ float sspf(float x) {
    // softplus(x) - log(2), numerically stable
    return fmaxf(x, 0.0f) + log1pf(expf(-fabsf(x))) - 0.69314718055994530942f;
}
__device__ __forceinline__ float4 ssp4(float4 v) {
    v.x = sspf(v.x); v.y = sspf(v.y); v.z = sspf(v.z); v.w = sspf(v.w);
    return v;
}
__device__ __forceinline__ float swishf(float x) {
    return x / (1.0f + expf(-x));
}

// -------------------------------------------------------------------------
// emb[n][0:64]  = swish(sin(t*coef_k)),  emb[n][64:128] = swish(cos(t*coef_k))
__global__ __launch_bounds__(256) void emb_kernel(const float* __restrict__ tt,
                                                  float* __restrict__ emb, int n) {
    int i = blockIdx.x * blockDim.x + threadIdx.x;
    if (i >= n * 64) return;
    int node = i >> 6, k = i & 63;
    float t = tt[node];
    float coef = expf((float)k * (-6.9077552789821368f / 63.0f));
    float e = t * coef;
    emb[node * NF + k]      = swishf(sinf(e));
    emb[node * NF + 64 + k] = swishf(cosf(e));
}

// -------------------------------------------------------------------------
// out[N,128] = f(A[N,128] @ W[128,128] (+bias) (+extra))
// MODE 0: plain (no bias).  MODE 1: ssp(.+b).  MODE 2: ssp(.+b+extra).  MODE 3: .+b
template<int MODE>
__global__ __launch_bounds__(256) void node_gemm(const float* __restrict__ A,
                                                 const float* __restrict__ W,
                                                 const float* __restrict__ bias,
                                                 const float* __restrict__ extra,
                                                 float* __restrict__ out, int n) {
    extern __shared__ float sm[];
    float* W_lds = sm;            // 128*128
    float* A_lds = sm + NF * NF;  // 32*128
    const int tid = threadIdx.x;
    const int cg = tid & 31;      // channel group: 4 channels 4*cg..
    const int rg = tid >> 5;      // row group: rows rg*4..rg*4+3 within tile

    for (int idx = tid * 4; idx < NF * NF; idx += 1024)
        st4(W_lds + idx, ld4(W + idx));

    float4 bv = make_float4(0.f, 0.f, 0.f, 0.f);
    if (MODE != 0) bv = ld4(bias + 4 * cg);

    const int ntile = (n + 31) >> 5;
    for (int tile = blockIdx.x; tile < ntile; tile += gridDim.x) {
        const int base = tile << 5;
        __syncthreads();
        for (int idx = tid * 4; idx < 32 * NF; idx += 1024) {
            int r = idx >> 7;
            int row = base + r;
            float4 v = make_float4(0.f, 0.f, 0.f, 0.f);
            if (row < n) v = ld4(A + row * NF + (idx & 127));
            st4(A_lds + idx, v);
        }
        __syncthreads();

        float4 acc[4] = {bv, bv, bv, bv};
        #pragma unroll 8
        for (int k4 = 0; k4 < 32; k4++) {
            float4 w0 = ld4(W_lds + (4 * k4 + 0) * NF + 4 * cg);
            float4 w1 = ld4(W_lds + (4 * k4 + 1) * NF + 4 * cg);
            float4 w2 = ld4(W_lds + (4 * k4 + 2) * NF + 4 * cg);
            float4 w3 = ld4(W_lds + (4 * k4 + 3) * NF + 4 * cg);
            #pragma unroll
            for (int rr = 0; rr < 4; rr++) {
                float4 a = ld4(A_lds + (rg * 4 + rr) * NF + 4 * k4);
                acc[rr] = f4fma(a.x, w0, acc[rr]);
                acc[rr] = f4fma(a.y, w1, acc[rr]);
                acc[rr] = f4fma(a.z, w2, acc[rr]);
                acc[rr] = f4fma(a.w, w3, acc[rr]);
            }
        }
        #pragma unroll
        for (int rr = 0; rr < 4; rr++) {
            int row = base + rg * 4 + rr;
            if (row >= n) continue;
            float4 v = acc[rr];
            if (MODE == 2) {
                float4 e4 = ld4(extra + row * NF + 4 * cg);
                v.x += e4.x; v.y += e4.y; v.z += e4.z; v.w += e4.w;
            }
            if (MODE == 1 || MODE == 2) v = ssp4(v);
            st4(out + row * NF + 4 * cg, v);
        }
    }
}

// -------------------------------------------------------------------------
// Fused edge kernel: Wf = (ssp(ea@em1+b1)@em2+b2)*C ; agg[dst] += y[src]*Wf
// Weights read from global (L1/L2-resident); LDS holds only per-tile data
// (34.3 KB -> 4 blocks/CU, 16 waves/CU).
__global__ __launch_bounds__(256, 4) void edge_conv(const float* __restrict__ y,
                                                    const int* __restrict__ ei,
                                                    const float* __restrict__ elen,
                                                    const float* __restrict__ eattr,
                                                    const float* __restrict__ em1w,
                                                    const float* __restrict__ em1b,
                                                    const float* __restrict__ em2w,
                                                    const float* __restrict__ em2b,
                                                    float* __restrict__ agg, int E_) {
    extern __shared__ float sm[];
    float* ea_lds  = sm;                      // ETILE*ECP (cols 50,51 zeroed)
    float* h_lds   = ea_lds + ETILE * ECP;    // ETILE*NF
    float* C_sm    = h_lds + ETILE * NF;      // ETILE
    int*   src_s   = (int*)(C_sm + ETILE);    // ETILE
    int*   dst_s   = src_s + ETILE;           // ETILE

    const int tid = threadIdx.x;
    const int cg = tid & 31;   // channel group (4 channels)
    const int eg = tid >> 5;   // edge slot group, RE edges each
    const int myE = eg * RE;

    const float4 zero4 = make_float4(0.f, 0.f, 0.f, 0.f);
    const float4 b1 = ld4(em1b + 4 * cg);
    const float4 b2 = ld4(em2b + 4 * cg);

    const int ntiles = (E_ + ETILE - 1) / ETILE;
    for (int tile = blockIdx.x; tile < ntiles; tile += gridDim.x) {
        const int base = tile * ETILE;
        __syncthreads();
        // stage edge meta
        for (int i = tid; i < ETILE; i += 256) {
            int e = base + i;
            float Cv = 0.0f; int s = 0, d = 0;
            if (e < E_) {
                s = ei[e]; d = ei[E_ + e];
                float len = elen[e];
                float c = 0.5f * (cosf(len * (PI_F / CUTOFF)) + 1.0f);
                Cv = (len <= CUTOFF && len >= 0.0f) ? c : 0.0f;
            }
            C_sm[i] = Cv; src_s[i] = s; dst_s[i] = d;
        }
        // stage edge_attr (zero-padded cols 50,51); coalesced global read
        for (int idx = tid; idx < ETILE * EC; idx += 256) {
            int i = idx / EC, k = idx - i * EC;
            int e = base + i;
            ea_lds[i * ECP + k] = (e < E_) ? eattr[(size_t)e * EC + k] : 0.0f;
        }
        for (int i = tid; i < ETILE * 2; i += 256)
            ea_lds[(i >> 1) * ECP + EC + (i & 1)] = 0.0f;
        __syncthreads();

        // ---- h = ssp(ea @ em1 + b1), each thread: 4 channels x RE edges
        float4 acc[RE];
        #pragma unroll
        for (int r = 0; r < RE; r++) acc[r] = b1;
        #pragma unroll
        for (int k4 = 0; k4 < ECP / 4; k4++) {
            float4 w0 = ld4(em1w + (4 * k4 + 0) * NF + 4 * cg);
            float4 w1 = ld4(em1w + (4 * k4 + 1) * NF + 4 * cg);
            float4 w2 = (4 * k4 + 2 < EC) ? ld4(em1w + (4 * k4 + 2) * NF + 4 * cg) : zero4;
            float4 w3 = (4 * k4 + 3 < EC) ? ld4(em1w + (4 * k4 + 3) * NF + 4 * cg) : zero4;
            #pragma unroll
            for (int r = 0; r < RE; r++) {
                float4 a = ld4(ea_lds + (myE + r) * ECP + 4 * k4);
                acc[r] = f4fma(a.x, w0, acc[r]);
                acc[r] = f4fma(a.y, w1, acc[r]);
                acc[r] = f4fma(a.z, w2, acc[r]);
                acc[r] = f4fma(a.w, w3, acc[r]);
            }
        }
        #pragma unroll
        for (int r = 0; r < RE; r++)
            st4(h_lds + (myE + r) * NF + 4 * cg, ssp4(acc[r]));
        __syncthreads();

        // ---- wf = h @ em2 + b2
        #pragma unroll
        for (int r = 0; r < RE; r++) acc[r] = b2;
        #pragma unroll 4
        for (int j4 = 0; j4 < NF / 4; j4++) {
            float4 w0 = ld4(em2w + (4 * j4 + 0) * NF + 4 * cg);
            float4 w1 = ld4(em2w + (4 * j4 + 1) * NF + 4 * cg);
            float4 w2 = ld4(em2w + (4 * j4 + 2) * NF + 4 * cg);
            float4 w3 = ld4(em2w + (4 * j4 + 3) * NF + 4 * cg);
            #pragma unroll
            for (int r = 0; r < RE; r++) {
                float4 h4 = ld4(h_lds + (myE + r) * NF + 4 * j4);
                acc[r] = f4fma(h4.x, w0, acc[r]);
                acc[r] = f4fma(h4.y, w1, acc[r]);
                acc[r] = f4fma(h4.z, w2, acc[r]);
                acc[r] = f4fma(h4.w, w3, acc[r]);
            }
        }

        // ---- epilogue: msg = y[src]*wf*C ; agg[dst] += msg
        #pragma unroll
        for (int r = 0; r < RE; r++) {
            int i = myE + r;
            int e = base + i;
            if (e >= E_) continue;
            float Cv = C_sm[i];
            if (Cv == 0.0f) continue;
            int s = src_s[i], d = dst_s[i];
            float4 yv = ld4(y + (size_t)s * NF + 4 * cg);
            float* ap = agg + (size_t)d * NF + 4 * cg;
            unsafeAtomicAdd(ap + 0, acc[r].x * Cv * yv.x);
            unsafeAtomicAdd(ap + 1, acc[r].y * Cv * yv.y);
            unsafeAtomicAdd(ap + 2, acc[r].z * Cv * yv.z);
            unsafeAtomicAdd(ap + 3, acc[r].w * Cv * yv.w);
        }
    }
}

// -------------------------------------------------------------------------
extern "C" void kernel_launch(void* const* d_in, const int* in_sizes, int n_in,
                              void* d_out, int out_size, void* d_ws, size_t ws_size,
                              hipStream_t stream) {
    const float* tt    = (const float*)d_in[0];
    const float* xx    = (const float*)d_in[1];
    const int*   ei    = (const int*)d_in[2];
    const float* elen  = (const float*)d_in[3];
    const float* eattr = (const float*)d_in[4];
    const float* em1w  = (const float*)d_in[5];
    const float* em1b  = (const float*)d_in[6];
    const float* em2w  = (const float*)d_in[7];
    const float* em2b  = (const float*)d_in[8];
    const float* c1m1w = (const float*)d_in[9];
    const float* c1m2w = (const float*)d_in[10];
    const float* c1m2b = (const float*)d_in[11];
    const float* c2m1w = (const float*)d_in[12];
    const float* c2m2w = (const float*)d_in[13];
    const float* c2m2b = (const float*)d_in[14];
    const float* tew   = (const float*)d_in[15];
    const float* teb   = (const float*)d_in[16];
    const float* linw  = (const float*)d_in[17];
    const float* linb  = (const float*)d_in[18];

    const int n  = in_sizes[0];      // N (tt is [N,1])
    const int E_ = in_sizes[2] / 2;  // edge_index is [2,E]
    float* out = (float*)d_out;

    const size_t NB = (size_t)n * NF;
    float* B0 = (float*)d_ws;   // y
    float* B1 = B0 + NB;        // agg
    float* B2 = B1 + NB;        // emb / x_mid
    float* B3 = B2 + NB;        // t / x3

    const size_t gemm_shmem = (size_t)(NF * NF + 32 * NF) * sizeof(float);   // 80 KB
    const size_t edge_shmem = (size_t)(ETILE * ECP + ETILE * NF + ETILE) * sizeof(float) +
                              (size_t)(2 * ETILE) * sizeof(int);             // ~34.3 KB

    // time embedding -> B2 ; t = swish_emb @ te_w + te_b -> B3
    emb_kernel<<<(n * 64 + 255) / 256, 256, 0, stream>>>(tt, B2, n);
    node_gemm<3><<<512, 256, gemm_shmem, stream>>>(B2, tew, teb, nullptr, B3, n);

    // y1 = xx @ c1_m1w -> B0
    node_gemm<0><<<512, 256, gemm_shmem, stream>>>(xx, c1m1w, nullptr, nullptr, B0, n);

    // conv1 scatter
    hipMemsetAsync(B1, 0, NB * sizeof(float), stream);
    edge_conv<<<1024, 256, edge_shmem, stream>>>(B0, ei, elen, eattr,
                                                 em1w, em1b, em2w, em2b, B1, E_);

    // x_mid = ssp(agg @ c1_m2w + b + t) -> B2
    node_gemm<2><<<512, 256, gemm_shmem, stream>>>(B1, c1m2w, c1m2b, B3, B2, n);

    // y2 = x_mid @ c2_m1w -> B0
    node_gemm<0><<<512, 256, gemm_shmem, stream>>>(B2, c2m1w, nullptr, nullptr, B0, n);

    // conv2 scatter
    hipMemsetAsync(B1, 0, NB * sizeof(float), stream);
    edge_conv<<<1024, 256, edge_shmem, stream>>>(B0, ei, elen, eattr,
                                                 em1w, em1b, em2w, em2b, B1, E_);

    // x3 = ssp(agg @ c2_m2w + b) -> B3 ; out = ssp(x3 @ lin_w + b)
    node_gemm<1><<<512, 256, gemm_shmem, stream>>>(B1, c2m2w, c2m2b, nullptr, B3, n);
    node_gemm<1><<<512, 256, gemm_shmem, stream>>>(B3, linw, linb, nullptr, out, n);
}

// Round 3
// 1729.228 us; speedup vs baseline: 2.1475x; 1.9171x over previous
//
#include <hip/hip_runtime.h>
#include <hip/hip_bf16.h>
#include <math.h>

#define NF 128
#define EC 50
#define ETILE 64
#define CUTOFF 0.8f
#define PI_F 3.14159265358979323846f

typedef __attribute__((ext_vector_type(8))) _Float16 f16x8;
typedef __attribute__((ext_vector_type(4))) float f32x4;

__device__ __forceinline__ float4 ld4(const float* p) { return *reinterpret_cast<const float4*>(p); }
__device__ __forceinline__ void st4(float* p, float4 v) { *reinterpret_cast<float4*>(p) = v; }

__device__ __forceinline__ float4 f4fma(float a, float4 w, float4 acc) {
    acc.x = fmaf(a, w.x, acc.x); acc.y = fmaf(a, w.y, acc.y);
    acc.z = fmaf(a, w.z, acc.z); acc.w = fmaf(a, w.w, acc.w);
    return acc;
}

__device__ __forceinline__ float sspf(float x) {
    // softplus(x) - log(2), numerically stable
    return fmaxf(x, 0.0f) + log1pf(expf(-fabsf(x))) - 0.69314718055994530942f;
}
__device__ __forceinline__ float4 ssp4(float4 v) {
    v.x = sspf(v.x); v.y = sspf(v.y); v.z = sspf(v.z); v.w = sspf(v.w);
    return v;
}
__device__ __forceinline__ float swishf(float x) {
    return x / (1.0f + expf(-x));
}

// -------------------------------------------------------------------------
// emb[n][0:64]  = swish(sin(t*coef_k)),  emb[n][64:128] = swish(cos(t*coef_k))
__global__ __launch_bounds__(256) void emb_kernel(const float* __restrict__ tt,
                                                  float* __restrict__ emb, int n) {
    int i = blockIdx.x * blockDim.x + threadIdx.x;
    if (i >= n * 64) return;
    int node = i >> 6, k = i & 63;
    float t = tt[node];
    float coef = expf((float)k * (-6.9077552789821368f / 63.0f));
    float e = t * coef;
    emb[node * NF + k]      = swishf(sinf(e));
    emb[node * NF + 64 + k] = swishf(cosf(e));
}

// -------------------------------------------------------------------------
// out[N,128] = f(A[N,128] @ W[128,128] (+bias) (+extra))
// MODE 0: plain (no bias).  MODE 1: ssp(.+b).  MODE 2: ssp(.+b+extra).  MODE 3: .+b
template<int MODE>
__global__ __launch_bounds__(256) void node_gemm(const float* __restrict__ A,
                                                 const float* __restrict__ W,
                                                 const float* __restrict__ bias,
                                                 const float* __restrict__ extra,
                                                 float* __restrict__ out, int n) {
    extern __shared__ float sm[];
    float* W_lds = sm;            // 128*128
    float* A_lds = sm + NF * NF;  // 32*128
    const int tid = threadIdx.x;
    const int cg = tid & 31;      // channel group: 4 channels 4*cg..
    const int rg = tid >> 5;      // row group: rows rg*4..rg*4+3 within tile

    for (int idx = tid * 4; idx < NF * NF; idx += 1024)
        st4(W_lds + idx, ld4(W + idx));

    float4 bv = make_float4(0.f, 0.f, 0.f, 0.f);
    if (MODE != 0) bv = ld4(bias + 4 * cg);

    const int ntile = (n + 31) >> 5;
    for (int tile = blockIdx.x; tile < ntile; tile += gridDim.x) {
        const int base = tile << 5;
        __syncthreads();
        for (int idx = tid * 4; idx < 32 * NF; idx += 1024) {
            int r = idx >> 7;
            int row = base + r;
            float4 v = make_float4(0.f, 0.f, 0.f, 0.f);
            if (row < n) v = ld4(A + row * NF + (idx & 127));
            st4(A_lds + idx, v);
        }
        __syncthreads();

        float4 acc[4] = {bv, bv, bv, bv};
        #pragma unroll 8
        for (int k4 = 0; k4 < 32; k4++) {
            float4 w0 = ld4(W_lds + (4 * k4 + 0) * NF + 4 * cg);
            float4 w1 = ld4(W_lds + (4 * k4 + 1) * NF + 4 * cg);
            float4 w2 = ld4(W_lds + (4 * k4 + 2) * NF + 4 * cg);
            float4 w3 = ld4(W_lds + (4 * k4 + 3) * NF + 4 * cg);
            #pragma unroll
            for (int rr = 0; rr < 4; rr++) {
                float4 a = ld4(A_lds + (rg * 4 + rr) * NF + 4 * k4);
                acc[rr] = f4fma(a.x, w0, acc[rr]);
                acc[rr] = f4fma(a.y, w1, acc[rr]);
                acc[rr] = f4fma(a.z, w2, acc[rr]);
                acc[rr] = f4fma(a.w, w3, acc[rr]);
            }
        }
        #pragma unroll
        for (int rr = 0; rr < 4; rr++) {
            int row = base + rg * 4 + rr;
            if (row >= n) continue;
            float4 v = acc[rr];
            if (MODE == 2) {
                float4 e4 = ld4(extra + row * NF + 4 * cg);
                v.x += e4.x; v.y += e4.y; v.z += e4.z; v.w += e4.w;
            }
            if (MODE == 1 || MODE == 2) v = ssp4(v);
            st4(out + row * NF + 4 * cg, v);
        }
    }
}

// -------------------------------------------------------------------------
// MFMA edge kernel (fp16 compute, f32 accumulate):
//   Wf = (ssp(ea@em1+b1)@em2+b2)*C ; agg[dst] += y[src]*Wf
// 64-edge tiles; 4 waves x 2 col-tiles (16 ch each); weight B-frags in VGPRs;
// ea/h staged in LDS fp16 with XOR swizzle (byte ^= (row&7)<<4) for
// conflict-free ds_read_b128 A-frags.
__global__ __launch_bounds__(256, 3) void edge_conv(const float* __restrict__ y,
                                                    const int* __restrict__ ei,
                                                    const float* __restrict__ elen,
                                                    const float* __restrict__ eattr,
                                                    const float* __restrict__ em1w,
                                                    const float* __restrict__ em1b,
                                                    const float* __restrict__ em2w,
                                                    const float* __restrict__ em2b,
                                                    float* __restrict__ agg, int E_) {
    extern __shared__ char smc[];
    char* ea_b = smc;                          // [64][128B] fp16 (K padded to 64)
    char* h_b  = smc + 64 * 128;               // [64][256B] fp16
    float* C_sm = (float*)(smc + 64 * 128 + 64 * 256);
    int* src_s = (int*)(C_sm + ETILE);
    int* dst_s = src_s + ETILE;

    const int tid  = threadIdx.x;
    const int wid  = tid >> 6;      // wave 0..3 -> channel tiles 2*wid, 2*wid+1
    const int lane = tid & 63;
    const int l15  = lane & 15;
    const int lhi  = lane >> 4;     // 0..3

    // ---- preload weight B-frags into registers (one-time per block)
    // B-frag layout (16x16x32): lane holds W[k = t*32 + lhi*8 + j][col = ct*16 + l15]
    f16x8 w1f[2][2];   // [ctile][kstep], em1 K padded 50->64
    f16x8 w2f[2][4];   // [ctile][kstep], em2 K=128
    float b1c[2], b2c[2];
    #pragma unroll
    for (int ct = 0; ct < 2; ct++) {
        const int col = (2 * wid + ct) * 16 + l15;
        b1c[ct] = em1b[col];
        b2c[ct] = em2b[col];
        #pragma unroll
        for (int t = 0; t < 2; t++) {
            #pragma unroll
            for (int j = 0; j < 8; j++) {
                int k = t * 32 + lhi * 8 + j;
                w1f[ct][t][j] = (_Float16)((k < EC) ? em1w[k * NF + col] : 0.0f);
            }
        }
        #pragma unroll
        for (int t = 0; t < 4; t++) {
            #pragma unroll
            for (int j = 0; j < 8; j++) {
                int k = t * 32 + lhi * 8 + j;
                w2f[ct][t][j] = (_Float16)em2w[k * NF + col];
            }
        }
    }

    const int ntiles = (E_ + ETILE - 1) / ETILE;
    for (int tile = blockIdx.x; tile < ntiles; tile += gridDim.x) {
        const int base = tile * ETILE;
        __syncthreads();   // protect meta/h from previous iteration's readers

        // ---- stage edge meta
        for (int i = tid; i < ETILE; i += 256) {
            int e = base + i;
            float Cv = 0.0f; int s = 0, d = 0;
            if (e < E_) {
                s = ei[e]; d = ei[E_ + e];
                float len = elen[e];
                float c = 0.5f * (cosf(len * (PI_F / CUTOFF)) + 1.0f);
                Cv = (len <= CUTOFF && len >= 0.0f) ? c : 0.0f;
            }
            C_sm[i] = Cv; src_s[i] = s; dst_s[i] = d;
        }
        // ---- stage ea: [64 edges][64 k] fp16, XOR-swizzled rows
        for (int idx = tid; idx < 64 * 64; idx += 256) {
            int row = idx >> 6, k = idx & 63;
            int e = base + row;
            float v = (k < EC && e < E_) ? eattr[(size_t)e * EC + k] : 0.0f;
            int off = row * 128 + ((2 * k) ^ ((row & 7) << 4));
            *(_Float16*)(ea_b + off) = (_Float16)v;
        }
        __syncthreads();

        // ---- layer 1: h = ssp(ea @ em1 + b1)
        f32x4 acc[4][2];
        #pragma unroll
        for (int m = 0; m < 4; m++)
            #pragma unroll
            for (int ct = 0; ct < 2; ct++) {
                f32x4 b = {b1c[ct], b1c[ct], b1c[ct], b1c[ct]};
                acc[m][ct] = b;
            }
        #pragma unroll
        for (int m = 0; m < 4; m++) {
            const int row = m * 16 + l15;
            #pragma unroll
            for (int t = 0; t < 2; t++) {
                int off = row * 128 + ((t * 64 + (lhi << 4)) ^ ((row & 7) << 4));
                f16x8 a = *(const f16x8*)(ea_b + off);
                #pragma unroll
                for (int ct = 0; ct < 2; ct++)
                    acc[m][ct] = __builtin_amdgcn_mfma_f32_16x16x32_f16(
                        a, w1f[ct][t], acc[m][ct], 0, 0, 0);
            }
        }
        // ssp + store h to LDS (fp16, swizzled). D layout: row=(lhi*4+r), col=l15.
        #pragma unroll
        for (int m = 0; m < 4; m++) {
            #pragma unroll
            for (int ct = 0; ct < 2; ct++) {
                const int col = (2 * wid + ct) * 16 + l15;
                #pragma unroll
                for (int r = 0; r < 4; r++) {
                    int row = m * 16 + lhi * 4 + r;
                    int off = row * 256 + ((2 * col) ^ ((row & 7) << 4));
                    *(_Float16*)(h_b + off) = (_Float16)sspf(acc[m][ct][r]);
                }
            }
        }
        __syncthreads();

        // ---- layer 2: wf = h @ em2 + b2
        #pragma unroll
        for (int m = 0; m < 4; m++)
            #pragma unroll
            for (int ct = 0; ct < 2; ct++) {
                f32x4 b = {b2c[ct], b2c[ct], b2c[ct], b2c[ct]};
                acc[m][ct] = b;
            }
        #pragma unroll
        for (int m = 0; m < 4; m++) {
            const int row = m * 16 + l15;
            #pragma unroll
            for (int t = 0; t < 4; t++) {
                int off = row * 256 + ((t * 64 + (lhi << 4)) ^ ((row & 7) << 4));
                f16x8 a = *(const f16x8*)(h_b + off);
                #pragma unroll
                for (int ct = 0; ct < 2; ct++)
                    acc[m][ct] = __builtin_amdgcn_mfma_f32_16x16x32_f16(
                        a, w2f[ct][t], acc[m][ct], 0, 0, 0);
            }
        }

        // ---- epilogue: agg[dst] += wf * C * y[src]
        #pragma unroll
        for (int m = 0; m < 4; m++) {
            #pragma unroll
            for (int r = 0; r < 4; r++) {
                int elocal = m * 16 + lhi * 4 + r;
                int e = base + elocal;
                if (e >= E_) continue;
                float Cv = C_sm[elocal];
                if (Cv == 0.0f) continue;
                int s = src_s[elocal], d = dst_s[elocal];
                #pragma unroll
                for (int ct = 0; ct < 2; ct++) {
                    int ch = (2 * wid + ct) * 16 + l15;
                    float w = acc[m][ct][r] * Cv;
                    float yv = y[(size_t)s * NF + ch];
                    unsafeAtomicAdd(agg + (size_t)d * NF + ch, w * yv);
                }
            }
        }
    }
}

// -------------------------------------------------------------------------
extern "C" void kernel_launch(void* const* d_in, const int* in_sizes, int n_in,
                              void* d_out, int out_size, void* d_ws, size_t ws_size,
                              hipStream_t stream) {
    const float* tt    = (const float*)d_in[0];
    const float* xx    = (const float*)d_in[1];
    const int*   ei    = (const int*)d_in[2];
    const float* elen  = (const float*)d_in[3];
    const float* eattr = (const float*)d_in[4];
    const float* em1w  = (const float*)d_in[5];
    const float* em1b  = (const float*)d_in[6];
    const float* em2w  = (const float*)d_in[7];
    const float* em2b  = (const float*)d_in[8];
    const float* c1m1w = (const float*)d_in[9];
    const float* c1m2w = (const float*)d_in[10];
    const float* c1m2b = (const float*)d_in[11];
    const float* c2m1w = (const float*)d_in[12];
    const float* c2m2w = (const float*)d_in[13];
    const float* c2m2b = (const float*)d_in[14];
    const float* tew   = (const float*)d_in[15];
    const float* teb   = (const float*)d_in[16];
    const float* linw  = (const float*)d_in[17];
    const float* linb  = (const float*)d_in[18];

    const int n  = in_sizes[0];      // N (tt is [N,1])
    const int E_ = in_sizes[2] / 2;  // edge_index is [2,E]
    float* out = (float*)d_out;

    const size_t NB = (size_t)n * NF;
    float* B0 = (float*)d_ws;   // y
    float* B1 = B0 + NB;        // agg
    float* B2 = B1 + NB;        // emb / x_mid
    float* B3 = B2 + NB;        // t / x3

    const size_t gemm_shmem = (size_t)(NF * NF + 32 * NF) * sizeof(float);   // 80 KB
    const size_t edge_shmem = (size_t)(64 * 128 + 64 * 256) +                // ea + h fp16
                              (size_t)ETILE * sizeof(float) +                // C
                              (size_t)(2 * ETILE) * sizeof(int);             // src,dst ~25.3 KB

    // time embedding -> B2 ; t = swish_emb @ te_w + te_b -> B3
    emb_kernel<<<(n * 64 + 255) / 256, 256, 0, stream>>>(tt, B2, n);
    node_gemm<3><<<512, 256, gemm_shmem, stream>>>(B2, tew, teb, nullptr, B3, n);

    // y1 = xx @ c1_m1w -> B0
    node_gemm<0><<<512, 256, gemm_shmem, stream>>>(xx, c1m1w, nullptr, nullptr, B0, n);

    // conv1 scatter
    hipMemsetAsync(B1, 0, NB * sizeof(float), stream);
    edge_conv<<<1024, 256, edge_shmem, stream>>>(B0, ei, elen, eattr,
                                                 em1w, em1b, em2w, em2b, B1, E_);

    // x_mid = ssp(agg @ c1_m2w + b + t) -> B2
    node_gemm<2><<<512, 256, gemm_shmem, stream>>>(B1, c1m2w, c1m2b, B3, B2, n);

    // y2 = x_mid @ c2_m1w -> B0
    node_gemm<0><<<512, 256, gemm_shmem, stream>>>(B2, c2m1w, nullptr, nullptr, B0, n);

    // conv2 scatter
    hipMemsetAsync(B1, 0, NB * sizeof(float), stream);
    edge_conv<<<1024, 256, edge_shmem, stream>>>(B0, ei, elen, eattr,
                                                 em1w, em1b, em2w, em2b, B1, E_);

    // x3 = ssp(agg @ c2_m2w + b) -> B3 ; out = ssp(x3 @ lin_w + b)
    node_gemm<1><<<512, 256, gemm_shmem, stream>>>(B1, c2m2w, c2m2b, nullptr, B3, n);
    node_gemm<1><<<512, 256, gemm_shmem, stream>>>(B3, linw, linb, nullptr, out, n);
}